// Round 10
// baseline (941.098 us; speedup 1.0000x reference)
//
#include <hip/hip_runtime.h>

// LSTM decoder: B=256, H=512, L=2, T=64, O=7
// Round 17 = r14 banked baseline (821.9us PASS) + ACK-OVERLAP only:
//  - r16's direct f32 weight load REVERTED (it cost +28us in-kernel:
//    2x per-WG weight bytes + startup serialization; Wc prologue restored).
//  - ack-overlap (the only isolated low-register-pressure lever left):
//    (1) consumer poll moved to tid 64 (wave 1);
//    (2) trailing __syncthreads between vmcnt(0) and the flag add DELETED.
//    The flag only requires wave 0's own store visibility (wave 0 issues all
//    64 stores; vmcnt(0) is wave-0 program order; the atomic cannot hoist
//    past the "memory"-clobbered asm). Next phase touches LDS only after its
//    post-poll barrier, which wave 0 reaches after store+ack -> all LDS
//    read/write pairs stay barrier-separated; vmcnt counts unchanged.
//  - everything else byte-identical to r14 (phase loop frozen: 6/6
//    restructurings failed under raised VGPR pressure; this change is +-0).

#define TT 64
#define NO 7

typedef _Float16 h16;
typedef __attribute__((ext_vector_type(8))) _Float16 half8;
typedef __attribute__((ext_vector_type(4))) float f32x4;
typedef __attribute__((ext_vector_type(4))) int i32x4;

__device__ __forceinline__ float sigf(float x)   { return 1.f / (1.f + __expf(-x)); }
__device__ __forceinline__ float tanhf_(float x) { return 1.f - 2.f / (__expf(2.f * x) + 1.f); }

// ---------------- fused prologue (r14, proven) ------------------------------
// blocks [0,2048): pack [W_ih | W_hh] -> f16 Wc[l][n][k], k-major
// blocks [2048,3600): Xinit/H0init/H1init + bias
// blocks [3600,3728): zero the 512KB flag array
__global__ __launch_bounds__(256) void prologue(
    const float* __restrict__ Wih, const float* __restrict__ Whh,
    h16* __restrict__ Wc,
    const float* __restrict__ x, const float* __restrict__ h0,
    const float* __restrict__ bih, const float* __restrict__ bhh,
    h16* __restrict__ Xinit, h16* __restrict__ H0init, h16* __restrict__ H1init,
    float* __restrict__ bias, unsigned* __restrict__ flags)
{
    int blk = blockIdx.x;
    if (blk < 2048) {
        size_t gid = (size_t)blk * 256 + threadIdx.x;
        size_t base = gid * 8;
        int l = (int)(base >> 21);
        int rem = (int)(base & ((1u << 21) - 1));
        int n = rem >> 10;
        int k = rem & 1023;
        const float* src = (k < 512)
            ? (Wih + ((size_t)l * 2048 + n) * 512 + k)
            : (Whh + ((size_t)l * 2048 + n) * 512 + (k - 512));
        const float4* s4 = (const float4*)src;
        float4 a = s4[0];
        float4 b = s4[1];
        half8 o;
        o[0] = (h16)a.x; o[1] = (h16)a.y; o[2] = (h16)a.z; o[3] = (h16)a.w;
        o[4] = (h16)b.x; o[5] = (h16)b.y; o[6] = (h16)b.z; o[7] = (h16)b.w;
        *(half8*)(Wc + base) = o;
        return;
    }
    blk -= 2048;
    if (blk < 1552) {
        int i = blk * 256 + threadIdx.x;
        if (i < 131072) { Xinit[i]  = (h16)x[i];           return; }
        i -= 131072;
        if (i < 131072) { H0init[i] = (h16)h0[i];          return; }
        i -= 131072;
        if (i < 131072) { H1init[i] = (h16)h0[131072 + i]; return; }
        i -= 131072;
        if (i < 4096) bias[i] = bih[i] + bhh[i];
        return;
    }
    blk -= 1552;
    i32x4 z = {0, 0, 0, 0};
    *(i32x4*)(flags + (size_t)(blk * 256 + threadIdx.x) * 4) = z;
}

// ---------------- persistent LSTM ------------------------------------------
// 256 WGs x 256 thr, 1 WG/CU. XCD-pinned: m = (wg&7)>>1, us = (wg>>3)+(wg&1)*32.
// WG: 64-row m-tile x 8 h-units. Wave w: rows (w>>1)*32..+32, units (w&1)*4..+4
// (16 gate-cols, col = 4*ulocal + gate).
__global__ __launch_bounds__(256, 1) void lstm_persist(
    const h16* __restrict__ Wc, const float* __restrict__ bias,
    const float* __restrict__ c0in,
    const h16* __restrict__ Xinit, const h16* __restrict__ H0init,
    const h16* __restrict__ H1init,
    h16* __restrict__ H0, h16* __restrict__ H1,
    float* __restrict__ h_st, float* __restrict__ c_st,
    unsigned* __restrict__ flags)
{
    __shared__ char ldsraw[65536];   // 2 x 32KB A-chunk double buffer

    const int wg   = blockIdx.x;
    const int m    = (wg & 7) >> 1;               // XCD-pinned m-group
    const int us   = (wg >> 3) + (wg & 1) * 32;   // unit slice 0..63
    const int myoct = us >> 3;
    const int tid  = threadIdx.x, w = tid >> 6, lane = tid & 63;
    const int u0   = us * 8;
    const int m0   = m * 64;
    const int rowbase = m0 + (w >> 1) * 32;
    const int ubase   = u0 + (w & 1) * 4;
    const int mcol = lane & 15, kq = lane >> 4;
    const int nrow = (mcol & 3) * 512 + ubase + (mcol >> 2);
    const int lrow = (w >> 1) * 32 + mcol;     // local row of m-subtile 0
    const int sw   = mcol & 7;                 // LDS XOR swizzle key
    const int lrloc = (w >> 1) * 32 + (lane >> 2);   // epilogue local row
    const int luloc = (w & 1) * 4 + (lane & 3);      // epilogue local unit

    // ---- B fragments for both layers -> registers/AGPRs (loaded once) ----
    half8 Bw0[32], Bw1[32];
#pragma unroll
    for (int ks = 0; ks < 32; ++ks) {
        Bw0[ks] = *(const half8*)(Wc + (size_t)nrow * 1024 + ks * 32 + kq * 8);
        Bw1[ks] = *(const half8*)(Wc + (size_t)(2048 + nrow) * 1024 + ks * 32 + kq * 8);
    }

    // ---- epilogue lane mapping (round-2/5/6 verified) ----
    const int eunit = ubase + (lane & 3);
    const int erow0 = rowbase + (lane >> 2);   // m-subtile 0; +16 for subtile 1
    float4 bz0 = make_float4(bias[eunit], bias[512 + eunit],
                             bias[1024 + eunit], bias[1536 + eunit]);
    float4 bz1 = make_float4(bias[2048 + eunit], bias[2048 + 512 + eunit],
                             bias[2048 + 1024 + eunit], bias[2048 + 1536 + eunit]);

    float creg[2][2], hreg[2][2];
#pragma unroll
    for (int mt = 0; mt < 2; ++mt) {
        creg[0][mt] = c0in[(erow0 + mt * 16) * 512 + eunit];
        creg[1][mt] = c0in[131072 + (erow0 + mt * 16) * 512 + eunit];
        hreg[0][mt] = 0.f; hreg[1][mt] = 0.f;
    }

// plain CACHED 16B loads of k-half `cs` (0/1) of the 64-row tile at BASE
// (row stride 1024B) into tmp[TB..TB+7]. Issue order defines vmcnt drains.
#define ISSUE_CHUNK(BASE, cs, TB) do {                                        \
    _Pragma("unroll")                                                         \
    for (int j = 0; j < 8; ++j) {                                             \
        int g = j * 256 + tid;                                                \
        int voff = (g >> 5) * 1024 + (cs) * 512 + (g & 31) * 16;              \
        asm volatile("global_load_dwordx4 %0, %1, %2"                         \
            : "=v"(tmp[(TB) + j]) : "v"(voff), "s"(BASE) : "memory");         \
    } } while (0)

// drain 8 loads (oldest-first) into LDS buffer `par` with XOR swizzle.
// NB = (outstanding when entering) - 1.
#define WRITE_CHUNK(par, TB, NB) do {                                         \
    _Pragma("unroll")                                                         \
    for (int j = 0; j < 8; ++j) {                                             \
        asm volatile("s_waitcnt vmcnt(%0)" :: "i"((NB) - j) : "memory");      \
        int g = j * 256 + tid;                                                \
        int row = g >> 5, bc = g & 31;                                        \
        *(i32x4*)(ldsraw + (par) * 32768 + row * 512 +                        \
                  ((bc ^ (row & 7)) * 16)) = tmp[(TB) + j];                   \
    } } while (0)

// 8 k-steps of MFMA from LDS buffer `par` against B fragments BW[CO..CO+7]
#define MFMA_CHUNK(par, CO, BW) do {                                          \
    _Pragma("unroll")                                                         \
    for (int ks = 0; ks < 8; ++ks) {                                          \
        half8 a0 = *(const half8*)(ldsraw + (par) * 32768 + lrow * 512 +      \
                      (((kq + 4 * ks) ^ sw) * 16));                           \
        half8 a1 = *(const half8*)(ldsraw + (par) * 32768 +                   \
                      (lrow + 16) * 512 + (((kq + 4 * ks) ^ sw) * 16));       \
        acc0 = __builtin_amdgcn_mfma_f32_16x16x32_f16(a0, (BW)[(CO) + ks],    \
                                                      acc0, 0, 0, 0);         \
        acc1 = __builtin_amdgcn_mfma_f32_16x16x32_f16(a1, (BW)[(CO) + ks],    \
                                                      acc1, 0, 0, 0);         \
    } } while (0)

// chunk order: h0 (k512-767, BW[16..23]), h1 (k768-1023, BW[24..31]),
//              x0 (k0-255,   BW[0..7]),   x1 (k256-511,  BW[8..15])
// h-chunks prefetched BEFORE the flag poll (their producer flag was polled one
// phase earlier => data complete; addresses write-once => caches never stale).
// ACK-OVERLAP: poll on tid 64 (wave 1); producer flag-add follows wave 0's
// own vmcnt(0) directly (no trailing barrier) - wave 0 issues all stores, so
// its program-order wait is sufficient for visibility before the flag.
#define PHASE(PH, WAIT, XSRC, HSRC, BW, BZ, CREG, HREG, HDST) do {            \
    const char* bx = (const char*)(XSRC) + (size_t)m0 * 1024;                 \
    const char* bh = (const char*)(HSRC) + (size_t)m0 * 1024;                 \
    i32x4 tmp[16];                                                            \
    ISSUE_CHUNK(bh, 0, 0);                                                    \
    ISSUE_CHUNK(bh, 1, 8);                                                    \
    if ((WAIT) && tid == 64) {                                                \
        unsigned* fb = flags + (((PH) - 1) * 4 + m) * 256;                    \
        for (;;) {                                                            \
            unsigned s = 0;                                                   \
            _Pragma("unroll")                                                 \
            for (int o = 0; o < 8; ++o)                                       \
                s += __hip_atomic_load(fb + o * 32, __ATOMIC_RELAXED,         \
                                       __HIP_MEMORY_SCOPE_SYSTEM);            \
            if (s == 64u) break;                                              \
            __builtin_amdgcn_s_sleep(1);                                      \
        }                                                                     \
    }                                                                         \
    __syncthreads();                                                          \
    f32x4 acc0 = {0.f,0.f,0.f,0.f}, acc1 = {0.f,0.f,0.f,0.f};                 \
    WRITE_CHUNK(0, 0, 15);                                                    \
    __syncthreads();                                                          \
    ISSUE_CHUNK(bx, 0, 0);                                                    \
    MFMA_CHUNK(0, 16, BW);                                                    \
    WRITE_CHUNK(1, 8, 15);                                                    \
    __syncthreads();                                                          \
    ISSUE_CHUNK(bx, 1, 8);                                                    \
    MFMA_CHUNK(1, 24, BW);                                                    \
    WRITE_CHUNK(0, 0, 15);                                                    \
    __syncthreads();                                                          \
    MFMA_CHUNK(0, 0, BW);                                                     \
    WRITE_CHUNK(1, 8, 7);                                                     \
    __syncthreads();                                                          \
    MFMA_CHUNK(1, 8, BW);                                                     \
    /* ---- epilogue: transpose, cell, LDS-gather, coalesced 16B flush ---- */ \
    float* scrw = (float*)(ldsraw + w * 1024);                                \
    h16* hbuf = (h16*)(ldsraw + 8192);                                        \
    _Pragma("unroll")                                                         \
    for (int mt = 0; mt < 2; ++mt) {                                          \
        f32x4 accv = mt ? acc1 : acc0;                                        \
        _Pragma("unroll")                                                     \
        for (int rr = 0; rr < 4; ++rr)                                        \
            scrw[(kq * 4 + rr) * 16 + mcol] = accv[rr];                       \
        float4 g4 = *(const float4*)&scrw[(lane >> 2) * 16 + (lane & 3) * 4]; \
        float iv = sigf(g4.x + (BZ).x);                                       \
        float fv = sigf(g4.y + (BZ).y);                                       \
        float gv = tanhf_(g4.z + (BZ).z);                                     \
        float ov = sigf(g4.w + (BZ).w);                                       \
        float cc = fv * (CREG)[mt] + iv * gv;                                 \
        float hh = ov * tanhf_(cc);                                           \
        (CREG)[mt] = cc; (HREG)[mt] = hh;                                     \
        hbuf[(lrloc + mt * 16) * 8 + luloc] = (h16)hh;                        \
    }                                                                         \
    __syncthreads();                                                          \
    if (tid < 64) {                                                           \
        i32x4 hv16 = *(const i32x4*)(ldsraw + 8192 + tid * 16);               \
        int voff = (m0 + tid) * 1024 + u0 * 2;                                \
        asm volatile("global_store_dwordx4 %0, %1, %2 sc0 sc1"                \
            :: "v"(voff), "v"(hv16), "s"(HDST) : "memory");                   \
    }                                                                         \
    asm volatile("s_waitcnt vmcnt(0)" ::: "memory");                          \
    if (tid == 0)                                                             \
        __hip_atomic_fetch_add(flags + (((PH) * 4 + m) * 8 + myoct) * 32, 1u, \
                               __ATOMIC_RELAXED, __HIP_MEMORY_SCOPE_AGENT);   \
} while (0)

#pragma unroll 1
    for (int t = 0; t < TT; ++t) {
        const h16* x0src = t ? (H1 + (size_t)(t - 1) * 131072) : Xinit;
        const h16* h0src = t ? (H0 + (size_t)(t - 1) * 131072) : H0init;
        // layer 0 (phase 2t): A = [x0src | h0src] -> H0[t]
        PHASE(2 * t, t > 0, x0src, h0src, Bw0, bz0, creg[0], hreg[0],
              (H0 + (size_t)t * 131072));
        const h16* h1src = t ? (H1 + (size_t)(t - 1) * 131072) : H1init;
        // layer 1 (phase 2t+1): A = [H0[t] | h1src] -> H1[t]
        PHASE(2 * t + 1, 1, (H0 + (size_t)t * 131072), h1src, Bw1, bz1,
              creg[1], hreg[1], (H1 + (size_t)t * 131072));
    }

    // ---- final hT / cT (normal stores; kernel-end release flushes) ----
#pragma unroll
    for (int mt = 0; mt < 2; ++mt) {
        int idx = (erow0 + mt * 16) * 512 + eunit;
        h_st[idx]          = hreg[0][mt];
        h_st[131072 + idx] = hreg[1][mt];
        c_st[idx]          = creg[0][mt];
        c_st[131072 + idx] = creg[1][mt];
    }
}

// ---------------- final FC over all stored h1(t): (T*B) x 7, K=512 -----------
__global__ __launch_bounds__(256) void fc_kernel(
    const h16* __restrict__ H1, const float* __restrict__ Wfc,
    const float* __restrict__ bfc, float* __restrict__ out)
{
    __shared__ float wl[NO * 512];
    for (int i = threadIdx.x; i < NO * 512; i += 256) wl[i] = Wfc[i];
    __syncthreads();
    const int wave = threadIdx.x >> 6, lane = threadIdx.x & 63;
    const int row = blockIdx.x * 4 + wave;   // row = t*256 + b
    const h16* hr = H1 + (size_t)row * 512;
    float acc[NO] = {0, 0, 0, 0, 0, 0, 0};
#pragma unroll
    for (int i = 0; i < 8; ++i) {
        float hv = (float)hr[i * 64 + lane];
#pragma unroll
        for (int o = 0; o < NO; ++o) acc[o] += hv * wl[o * 512 + i * 64 + lane];
    }
#pragma unroll
    for (int o = 0; o < NO; ++o)
#pragma unroll
        for (int off = 32; off; off >>= 1) acc[o] += __shfl_down(acc[o], off);
    if (lane == 0) {
        const int t = row >> 8, b = row & 255;
#pragma unroll
        for (int o = 0; o < NO; ++o) out[b * (TT * NO) + t * NO + o] = acc[o] + bfc[o];
    }
}

extern "C" void kernel_launch(void* const* d_in, const int* in_sizes, int n_in,
                              void* d_out, int out_size, void* d_ws, size_t ws_size,
                              hipStream_t stream)
{
    (void)in_sizes; (void)n_in; (void)out_size; (void)ws_size;
    const float* x   = (const float*)d_in[0];
    const float* h0  = (const float*)d_in[1];
    const float* c0  = (const float*)d_in[2];
    const float* Wih = (const float*)d_in[3];
    const float* Whh = (const float*)d_in[4];
    const float* bih = (const float*)d_in[5];
    const float* bhh = (const float*)d_in[6];
    const float* Wfc = (const float*)d_in[7];
    const float* bfc = (const float*)d_in[8];

    float* outf = (float*)d_out;                 // decoded (256*64*7)
    float* h_st = outf + 114688;                 // hT (2,256,512)
    float* c_st = h_st + 262144;                 // cT (2,256,512)

    char* ws = (char*)d_ws;
    h16*      Wc     = (h16*)ws;                         // 8 MB
    float*    bias   = (float*)(ws + 8388608);           // 16 KB
    h16*      Xinit  = (h16*)(ws + 8404992);             // 256 KB
    h16*      H0init = (h16*)(ws + 8667136);             // 256 KB
    h16*      H1init = (h16*)(ws + 8929280);             // 256 KB
    h16*      H0     = (h16*)(ws + 9191424);             // 16 MB (64 steps)
    h16*      H1     = (h16*)(ws + 25968640);            // 16 MB (64 steps)
    unsigned* flags  = (unsigned*)(ws + 42745856);       // 512 KB

    prologue<<<3728, 256, 0, stream>>>(Wih, Whh, Wc, x, h0, bih, bhh,
                                       Xinit, H0init, H1init, bias, flags);
    lstm_persist<<<256, 256, 0, stream>>>(Wc, bias, c0, Xinit, H0init, H1init,
                                          H0, H1, h_st, c_st, flags);
    fc_kernel<<<4096, 256, 0, stream>>>(H1, Wfc, bfc, outf);
}

// Round 11
// 819.485 us; speedup vs baseline: 1.1484x; 1.1484x over previous
//
#include <hip/hip_runtime.h>

// LSTM decoder: B=256, H=512, L=2, T=64, O=7
// FINAL = r14 (measured 821.9us PASS), resubmitted byte-identical.
// Session ledger: phase-loop/sync restructurings 0-for-7 (corruption x3,
// crash x1, 2x regression x1, 17% regression x1 [ack-overlap: flag-add
// queued behind next-phase load burst], infra x1). The serial chain
// (128 phases x max-over-64-producers of store-ack + flag + poll + staged
// compute) is the floor of this decomposition on this toolchain; peripheral
// work (prologue fusion) banked. Do not modify without disasm access.

#define TT 64
#define NO 7

typedef _Float16 h16;
typedef __attribute__((ext_vector_type(8))) _Float16 half8;
typedef __attribute__((ext_vector_type(4))) float f32x4;
typedef __attribute__((ext_vector_type(4))) int i32x4;

__device__ __forceinline__ float sigf(float x)   { return 1.f / (1.f + __expf(-x)); }
__device__ __forceinline__ float tanhf_(float x) { return 1.f - 2.f / (__expf(2.f * x) + 1.f); }

// ---------------- fused prologue -------------------------------------------
// blocks [0,2048): pack [W_ih | W_hh] -> f16 Wc[l][n][k], k-major (8 h16/thr)
// blocks [2048,3600): Xinit/H0init/H1init + bias
// blocks [3600,3728): zero the 512KB flag array (16B/thr)
__global__ __launch_bounds__(256) void prologue(
    const float* __restrict__ Wih, const float* __restrict__ Whh,
    h16* __restrict__ Wc,
    const float* __restrict__ x, const float* __restrict__ h0,
    const float* __restrict__ bih, const float* __restrict__ bhh,
    h16* __restrict__ Xinit, h16* __restrict__ H0init, h16* __restrict__ H1init,
    float* __restrict__ bias, unsigned* __restrict__ flags)
{
    int blk = blockIdx.x;
    if (blk < 2048) {
        size_t gid = (size_t)blk * 256 + threadIdx.x;
        size_t base = gid * 8;
        int l = (int)(base >> 21);
        int rem = (int)(base & ((1u << 21) - 1));
        int n = rem >> 10;
        int k = rem & 1023;
        const float* src = (k < 512)
            ? (Wih + ((size_t)l * 2048 + n) * 512 + k)
            : (Whh + ((size_t)l * 2048 + n) * 512 + (k - 512));
        const float4* s4 = (const float4*)src;
        float4 a = s4[0];
        float4 b = s4[1];
        half8 o;
        o[0] = (h16)a.x; o[1] = (h16)a.y; o[2] = (h16)a.z; o[3] = (h16)a.w;
        o[4] = (h16)b.x; o[5] = (h16)b.y; o[6] = (h16)b.z; o[7] = (h16)b.w;
        *(half8*)(Wc + base) = o;
        return;
    }
    blk -= 2048;
    if (blk < 1552) {
        int i = blk * 256 + threadIdx.x;
        if (i < 131072) { Xinit[i]  = (h16)x[i];           return; }
        i -= 131072;
        if (i < 131072) { H0init[i] = (h16)h0[i];          return; }
        i -= 131072;
        if (i < 131072) { H1init[i] = (h16)h0[131072 + i]; return; }
        i -= 131072;
        if (i < 4096) bias[i] = bih[i] + bhh[i];
        return;
    }
    blk -= 1552;
    // flags zero: 128 blocks x 256 threads x 16B = 512KB
    i32x4 z = {0, 0, 0, 0};
    *(i32x4*)(flags + (size_t)(blk * 256 + threadIdx.x) * 4) = z;
}

// ---------------- persistent LSTM (round-0 PROVEN kernel, verbatim) ---------
// 256 WGs x 256 thr, 1 WG/CU. XCD-pinned: m = (wg&7)>>1, us = (wg>>3)+(wg&1)*32.
// WG: 64-row m-tile x 8 h-units. Wave w: rows (w>>1)*32..+32, units (w&1)*4..+4
// (16 gate-cols, col = 4*ulocal + gate).
__global__ __launch_bounds__(256, 1) void lstm_persist(
    const h16* __restrict__ Wc, const float* __restrict__ bias,
    const float* __restrict__ c0in,
    const h16* __restrict__ Xinit, const h16* __restrict__ H0init,
    const h16* __restrict__ H1init,
    h16* __restrict__ H0, h16* __restrict__ H1,
    float* __restrict__ h_st, float* __restrict__ c_st,
    unsigned* __restrict__ flags)
{
    __shared__ char ldsraw[65536];   // 2 x 32KB A-chunk double buffer

    const int wg   = blockIdx.x;
    const int m    = (wg & 7) >> 1;               // XCD-pinned m-group
    const int us   = (wg >> 3) + (wg & 1) * 32;   // unit slice 0..63
    const int myoct = us >> 3;
    const int tid  = threadIdx.x, w = tid >> 6, lane = tid & 63;
    const int u0   = us * 8;
    const int m0   = m * 64;
    const int rowbase = m0 + (w >> 1) * 32;
    const int ubase   = u0 + (w & 1) * 4;
    const int mcol = lane & 15, kq = lane >> 4;
    const int nrow = (mcol & 3) * 512 + ubase + (mcol >> 2);
    const int lrow = (w >> 1) * 32 + mcol;     // local row of m-subtile 0
    const int sw   = mcol & 7;                 // LDS XOR swizzle key
    const int lrloc = (w >> 1) * 32 + (lane >> 2);   // epilogue local row
    const int luloc = (w & 1) * 4 + (lane & 3);      // epilogue local unit

    // ---- B fragments for both layers -> registers/AGPRs (loaded once) ----
    half8 Bw0[32], Bw1[32];
#pragma unroll
    for (int ks = 0; ks < 32; ++ks) {
        Bw0[ks] = *(const half8*)(Wc + (size_t)nrow * 1024 + ks * 32 + kq * 8);
        Bw1[ks] = *(const half8*)(Wc + (size_t)(2048 + nrow) * 1024 + ks * 32 + kq * 8);
    }

    // ---- epilogue lane mapping (round-2/5/6 verified) ----
    const int eunit = ubase + (lane & 3);
    const int erow0 = rowbase + (lane >> 2);   // m-subtile 0; +16 for subtile 1
    float4 bz0 = make_float4(bias[eunit], bias[512 + eunit],
                             bias[1024 + eunit], bias[1536 + eunit]);
    float4 bz1 = make_float4(bias[2048 + eunit], bias[2048 + 512 + eunit],
                             bias[2048 + 1024 + eunit], bias[2048 + 1536 + eunit]);

    float creg[2][2], hreg[2][2];
#pragma unroll
    for (int mt = 0; mt < 2; ++mt) {
        creg[0][mt] = c0in[(erow0 + mt * 16) * 512 + eunit];
        creg[1][mt] = c0in[131072 + (erow0 + mt * 16) * 512 + eunit];
        hreg[0][mt] = 0.f; hreg[1][mt] = 0.f;
    }

// plain CACHED 16B loads of k-half `cs` (0/1) of the 64-row tile at BASE
// (row stride 1024B) into tmp[TB..TB+7]. Issue order defines vmcnt drains.
#define ISSUE_CHUNK(BASE, cs, TB) do {                                        \
    _Pragma("unroll")                                                         \
    for (int j = 0; j < 8; ++j) {                                             \
        int g = j * 256 + tid;                                                \
        int voff = (g >> 5) * 1024 + (cs) * 512 + (g & 31) * 16;              \
        asm volatile("global_load_dwordx4 %0, %1, %2"                         \
            : "=v"(tmp[(TB) + j]) : "v"(voff), "s"(BASE) : "memory");         \
    } } while (0)

// drain 8 loads (oldest-first) into LDS buffer `par` with XOR swizzle.
// NB = (outstanding when entering) - 1.
#define WRITE_CHUNK(par, TB, NB) do {                                         \
    _Pragma("unroll")                                                         \
    for (int j = 0; j < 8; ++j) {                                             \
        asm volatile("s_waitcnt vmcnt(%0)" :: "i"((NB) - j) : "memory");      \
        int g = j * 256 + tid;                                                \
        int row = g >> 5, bc = g & 31;                                        \
        *(i32x4*)(ldsraw + (par) * 32768 + row * 512 +                        \
                  ((bc ^ (row & 7)) * 16)) = tmp[(TB) + j];                   \
    } } while (0)

// 8 k-steps of MFMA from LDS buffer `par` against B fragments BW[CO..CO+7]
#define MFMA_CHUNK(par, CO, BW) do {                                          \
    _Pragma("unroll")                                                         \
    for (int ks = 0; ks < 8; ++ks) {                                          \
        half8 a0 = *(const half8*)(ldsraw + (par) * 32768 + lrow * 512 +      \
                      (((kq + 4 * ks) ^ sw) * 16));                           \
        half8 a1 = *(const half8*)(ldsraw + (par) * 32768 +                   \
                      (lrow + 16) * 512 + (((kq + 4 * ks) ^ sw) * 16));       \
        acc0 = __builtin_amdgcn_mfma_f32_16x16x32_f16(a0, (BW)[(CO) + ks],    \
                                                      acc0, 0, 0, 0);         \
        acc1 = __builtin_amdgcn_mfma_f32_16x16x32_f16(a1, (BW)[(CO) + ks],    \
                                                      acc1, 0, 0, 0);         \
    } } while (0)

// chunk order: h0 (k512-767, BW[16..23]), h1 (k768-1023, BW[24..31]),
//              x0 (k0-255,   BW[0..7]),   x1 (k256-511,  BW[8..15])
// h-chunks prefetched BEFORE the flag poll (their producer flag was polled one
// phase earlier => data complete; addresses write-once => caches never stale).
#define PHASE(PH, WAIT, XSRC, HSRC, BW, BZ, CREG, HREG, HDST) do {            \
    const char* bx = (const char*)(XSRC) + (size_t)m0 * 1024;                 \
    const char* bh = (const char*)(HSRC) + (size_t)m0 * 1024;                 \
    i32x4 tmp[16];                                                            \
    ISSUE_CHUNK(bh, 0, 0);                                                    \
    ISSUE_CHUNK(bh, 1, 8);                                                    \
    if ((WAIT) && tid == 0) {                                                 \
        unsigned* fb = flags + (((PH) - 1) * 4 + m) * 256;                    \
        for (;;) {                                                            \
            unsigned s = 0;                                                   \
            _Pragma("unroll")                                                 \
            for (int o = 0; o < 8; ++o)                                       \
                s += __hip_atomic_load(fb + o * 32, __ATOMIC_RELAXED,         \
                                       __HIP_MEMORY_SCOPE_SYSTEM);            \
            if (s == 64u) break;                                              \
            __builtin_amdgcn_s_sleep(1);                                      \
        }                                                                     \
    }                                                                         \
    __syncthreads();                                                          \
    f32x4 acc0 = {0.f,0.f,0.f,0.f}, acc1 = {0.f,0.f,0.f,0.f};                 \
    WRITE_CHUNK(0, 0, 15);                                                    \
    __syncthreads();                                                          \
    ISSUE_CHUNK(bx, 0, 0);                                                    \
    MFMA_CHUNK(0, 16, BW);                                                    \
    WRITE_CHUNK(1, 8, 15);                                                    \
    __syncthreads();                                                          \
    ISSUE_CHUNK(bx, 1, 8);                                                    \
    MFMA_CHUNK(1, 24, BW);                                                    \
    WRITE_CHUNK(0, 0, 15);                                                    \
    __syncthreads();                                                          \
    MFMA_CHUNK(0, 0, BW);                                                     \
    WRITE_CHUNK(1, 8, 7);                                                     \
    __syncthreads();                                                          \
    MFMA_CHUNK(1, 8, BW);                                                     \
    /* ---- epilogue: transpose, cell, LDS-gather, coalesced 16B flush ---- */ \
    float* scrw = (float*)(ldsraw + w * 1024);                                \
    h16* hbuf = (h16*)(ldsraw + 8192);                                        \
    _Pragma("unroll")                                                         \
    for (int mt = 0; mt < 2; ++mt) {                                          \
        f32x4 accv = mt ? acc1 : acc0;                                        \
        _Pragma("unroll")                                                     \
        for (int rr = 0; rr < 4; ++rr)                                        \
            scrw[(kq * 4 + rr) * 16 + mcol] = accv[rr];                       \
        float4 g4 = *(const float4*)&scrw[(lane >> 2) * 16 + (lane & 3) * 4]; \
        float iv = sigf(g4.x + (BZ).x);                                       \
        float fv = sigf(g4.y + (BZ).y);                                       \
        float gv = tanhf_(g4.z + (BZ).z);                                     \
        float ov = sigf(g4.w + (BZ).w);                                       \
        float cc = fv * (CREG)[mt] + iv * gv;                                 \
        float hh = ov * tanhf_(cc);                                           \
        (CREG)[mt] = cc; (HREG)[mt] = hh;                                     \
        hbuf[(lrloc + mt * 16) * 8 + luloc] = (h16)hh;                        \
    }                                                                         \
    __syncthreads();                                                          \
    if (tid < 64) {                                                           \
        i32x4 hv16 = *(const i32x4*)(ldsraw + 8192 + tid * 16);               \
        int voff = (m0 + tid) * 1024 + u0 * 2;                                \
        asm volatile("global_store_dwordx4 %0, %1, %2 sc0 sc1"                \
            :: "v"(voff), "v"(hv16), "s"(HDST) : "memory");                   \
    }                                                                         \
    asm volatile("s_waitcnt vmcnt(0)" ::: "memory");                          \
    __syncthreads();                                                          \
    if (tid == 0)                                                             \
        __hip_atomic_fetch_add(flags + (((PH) * 4 + m) * 8 + myoct) * 32, 1u, \
                               __ATOMIC_RELAXED, __HIP_MEMORY_SCOPE_AGENT);   \
} while (0)

#pragma unroll 1
    for (int t = 0; t < TT; ++t) {
        const h16* x0src = t ? (H1 + (size_t)(t - 1) * 131072) : Xinit;
        const h16* h0src = t ? (H0 + (size_t)(t - 1) * 131072) : H0init;
        // layer 0 (phase 2t): A = [x0src | h0src] -> H0[t]
        PHASE(2 * t, t > 0, x0src, h0src, Bw0, bz0, creg[0], hreg[0],
              (H0 + (size_t)t * 131072));
        const h16* h1src = t ? (H1 + (size_t)(t - 1) * 131072) : H1init;
        // layer 1 (phase 2t+1): A = [H0[t] | h1src] -> H1[t]
        PHASE(2 * t + 1, 1, (H0 + (size_t)t * 131072), h1src, Bw1, bz1,
              creg[1], hreg[1], (H1 + (size_t)t * 131072));
    }

    // ---- final hT / cT (normal stores; kernel-end release flushes) ----
#pragma unroll
    for (int mt = 0; mt < 2; ++mt) {
        int idx = (erow0 + mt * 16) * 512 + eunit;
        h_st[idx]          = hreg[0][mt];
        h_st[131072 + idx] = hreg[1][mt];
        c_st[idx]          = creg[0][mt];
        c_st[131072 + idx] = creg[1][mt];
    }
}

// ---------------- final FC over all stored h1(t): (T*B) x 7, K=512 -----------
__global__ __launch_bounds__(256) void fc_kernel(
    const h16* __restrict__ H1, const float* __restrict__ Wfc,
    const float* __restrict__ bfc, float* __restrict__ out)
{
    __shared__ float wl[NO * 512];
    for (int i = threadIdx.x; i < NO * 512; i += 256) wl[i] = Wfc[i];
    __syncthreads();
    const int wave = threadIdx.x >> 6, lane = threadIdx.x & 63;
    const int row = blockIdx.x * 4 + wave;   // row = t*256 + b
    const h16* hr = H1 + (size_t)row * 512;
    float acc[NO] = {0, 0, 0, 0, 0, 0, 0};
#pragma unroll
    for (int i = 0; i < 8; ++i) {
        float hv = (float)hr[i * 64 + lane];
#pragma unroll
        for (int o = 0; o < NO; ++o) acc[o] += hv * wl[o * 512 + i * 64 + lane];
    }
#pragma unroll
    for (int o = 0; o < NO; ++o)
#pragma unroll
        for (int off = 32; off; off >>= 1) acc[o] += __shfl_down(acc[o], off);
    if (lane == 0) {
        const int t = row >> 8, b = row & 255;
#pragma unroll
        for (int o = 0; o < NO; ++o) out[b * (TT * NO) + t * NO + o] = acc[o] + bfc[o];
    }
}

extern "C" void kernel_launch(void* const* d_in, const int* in_sizes, int n_in,
                              void* d_out, int out_size, void* d_ws, size_t ws_size,
                              hipStream_t stream)
{
    (void)in_sizes; (void)n_in; (void)out_size; (void)ws_size;
    const float* x   = (const float*)d_in[0];
    const float* h0  = (const float*)d_in[1];
    const float* c0  = (const float*)d_in[2];
    const float* Wih = (const float*)d_in[3];
    const float* Whh = (const float*)d_in[4];
    const float* bih = (const float*)d_in[5];
    const float* bhh = (const float*)d_in[6];
    const float* Wfc = (const float*)d_in[7];
    const float* bfc = (const float*)d_in[8];

    float* outf = (float*)d_out;                 // decoded (256*64*7)
    float* h_st = outf + 114688;                 // hT (2,256,512)
    float* c_st = h_st + 262144;                 // cT (2,256,512)

    char* ws = (char*)d_ws;
    h16*      Wc     = (h16*)ws;                         // 8 MB
    float*    bias   = (float*)(ws + 8388608);           // 16 KB
    h16*      Xinit  = (h16*)(ws + 8404992);             // 256 KB
    h16*      H0init = (h16*)(ws + 8667136);             // 256 KB
    h16*      H1init = (h16*)(ws + 8929280);             // 256 KB
    h16*      H0     = (h16*)(ws + 9191424);             // 16 MB (64 steps)
    h16*      H1     = (h16*)(ws + 25968640);            // 16 MB (64 steps)
    unsigned* flags  = (unsigned*)(ws + 42745856);       // 512 KB

    prologue<<<3728, 256, 0, stream>>>(Wih, Whh, Wc, x, h0, bih, bhh,
                                       Xinit, H0init, H1init, bias, flags);
    lstm_persist<<<256, 256, 0, stream>>>(Wc, bias, c0, Xinit, H0init, H1init,
                                          H0, H1, h_st, c_st, flags);
    fc_kernel<<<4096, 256, 0, stream>>>(H1, Wfc, bfc, outf);
}

// Round 12
// 618.769 us; speedup vs baseline: 1.5209x; 1.3244x over previous
//
#include <hip/hip_runtime.h>

// LSTM decoder: B=256, H=512, L=2, T=64, O=7
// Round 18 = r14 skeleton + PER-THREAD OCT GATES (fine-grained flag wait):
//  - KEY: for a fixed thread, all 8 loads of chunk cs have g&31 = tid&31 ->
//    they read units [cs*256+(tid&31)*8,+8) = output of EXACTLY ONE producer
//    WG (us' = cs*32+(tid&31)) = one 8-producer sub-counter
//    (oct = cs*4 + ((tid&31)>>3)). Each thread gates its own x-loads on its
//    own oct counter (==8): no tid0 broadcast, no WG-wide max-of-64 wait.
//  - h-staging + h0-MFMA now run UNGATED (during producer lag); gates sit
//    immediately before ISSUE x0 / ISSUE x1.
//  - safety (vs the 0-for-7 ledger): each gate's atomic load makes the
//    compiler emit s_waitcnt vmcnt(0) (it tracks only its own load) ->
//    drains ALL asm loads into tmps. After a gate only the 8 post-gate
//    loads are outstanding, so every later counted wait is a no-op; on the
//    WAIT=0 path the counts are byte-identical to proven r14. Extra
//    compiler VMEM ops only make counted waits MORE conservative.
//  - accumulation order h0,h1,x0,x1 preserved -> bit-identical numerics.
//  - epilogue verbatim (incl. both trailing barriers - r17 proved the
//    store-ack must complete before the next load burst). Barriers: 7 (same).

#define TT 64
#define NO 7

typedef _Float16 h16;
typedef __attribute__((ext_vector_type(8))) _Float16 half8;
typedef __attribute__((ext_vector_type(4))) float f32x4;
typedef __attribute__((ext_vector_type(4))) int i32x4;

__device__ __forceinline__ float sigf(float x)   { return 1.f / (1.f + __expf(-x)); }
__device__ __forceinline__ float tanhf_(float x) { return 1.f - 2.f / (__expf(2.f * x) + 1.f); }

// ---------------- fused prologue (r14, proven) ------------------------------
// blocks [0,2048): pack [W_ih | W_hh] -> f16 Wc[l][n][k], k-major (8 h16/thr)
// blocks [2048,3600): Xinit/H0init/H1init + bias
// blocks [3600,3728): zero the 512KB flag array (16B/thr)
__global__ __launch_bounds__(256) void prologue(
    const float* __restrict__ Wih, const float* __restrict__ Whh,
    h16* __restrict__ Wc,
    const float* __restrict__ x, const float* __restrict__ h0,
    const float* __restrict__ bih, const float* __restrict__ bhh,
    h16* __restrict__ Xinit, h16* __restrict__ H0init, h16* __restrict__ H1init,
    float* __restrict__ bias, unsigned* __restrict__ flags)
{
    int blk = blockIdx.x;
    if (blk < 2048) {
        size_t gid = (size_t)blk * 256 + threadIdx.x;
        size_t base = gid * 8;
        int l = (int)(base >> 21);
        int rem = (int)(base & ((1u << 21) - 1));
        int n = rem >> 10;
        int k = rem & 1023;
        const float* src = (k < 512)
            ? (Wih + ((size_t)l * 2048 + n) * 512 + k)
            : (Whh + ((size_t)l * 2048 + n) * 512 + (k - 512));
        const float4* s4 = (const float4*)src;
        float4 a = s4[0];
        float4 b = s4[1];
        half8 o;
        o[0] = (h16)a.x; o[1] = (h16)a.y; o[2] = (h16)a.z; o[3] = (h16)a.w;
        o[4] = (h16)b.x; o[5] = (h16)b.y; o[6] = (h16)b.z; o[7] = (h16)b.w;
        *(half8*)(Wc + base) = o;
        return;
    }
    blk -= 2048;
    if (blk < 1552) {
        int i = blk * 256 + threadIdx.x;
        if (i < 131072) { Xinit[i]  = (h16)x[i];           return; }
        i -= 131072;
        if (i < 131072) { H0init[i] = (h16)h0[i];          return; }
        i -= 131072;
        if (i < 131072) { H1init[i] = (h16)h0[131072 + i]; return; }
        i -= 131072;
        if (i < 4096) bias[i] = bih[i] + bhh[i];
        return;
    }
    blk -= 1552;
    // flags zero: 128 blocks x 256 threads x 16B = 512KB
    i32x4 z = {0, 0, 0, 0};
    *(i32x4*)(flags + (size_t)(blk * 256 + threadIdx.x) * 4) = z;
}

// ---------------- persistent LSTM ------------------------------------------
// 256 WGs x 256 thr, 1 WG/CU. XCD-pinned: m = (wg&7)>>1, us = (wg>>3)+(wg&1)*32.
// WG: 64-row m-tile x 8 h-units. Wave w: rows (w>>1)*32..+32, units (w&1)*4..+4
// (16 gate-cols, col = 4*ulocal + gate).
__global__ __launch_bounds__(256, 1) void lstm_persist(
    const h16* __restrict__ Wc, const float* __restrict__ bias,
    const float* __restrict__ c0in,
    const h16* __restrict__ Xinit, const h16* __restrict__ H0init,
    const h16* __restrict__ H1init,
    h16* __restrict__ H0, h16* __restrict__ H1,
    float* __restrict__ h_st, float* __restrict__ c_st,
    unsigned* __restrict__ flags)
{
    __shared__ char ldsraw[65536];   // 2 x 32KB A-chunk double buffer

    const int wg   = blockIdx.x;
    const int m    = (wg & 7) >> 1;               // XCD-pinned m-group
    const int us   = (wg >> 3) + (wg & 1) * 32;   // unit slice 0..63
    const int myoct = us >> 3;
    const int tid  = threadIdx.x, w = tid >> 6, lane = tid & 63;
    const int u0   = us * 8;
    const int m0   = m * 64;
    const int rowbase = m0 + (w >> 1) * 32;
    const int ubase   = u0 + (w & 1) * 4;
    const int mcol = lane & 15, kq = lane >> 4;
    const int nrow = (mcol & 3) * 512 + ubase + (mcol >> 2);
    const int lrow = (w >> 1) * 32 + mcol;     // local row of m-subtile 0
    const int sw   = mcol & 7;                 // LDS XOR swizzle key
    const int lrloc = (w >> 1) * 32 + (lane >> 2);   // epilogue local row
    const int luloc = (w & 1) * 4 + (lane & 3);      // epilogue local unit
    const int octlo = (tid & 31) >> 3;         // producer oct of my x0 loads
    const int octhi = 4 + ((tid & 31) >> 3);   // producer oct of my x1 loads

    // ---- B fragments for both layers -> registers/AGPRs (loaded once) ----
    half8 Bw0[32], Bw1[32];
#pragma unroll
    for (int ks = 0; ks < 32; ++ks) {
        Bw0[ks] = *(const half8*)(Wc + (size_t)nrow * 1024 + ks * 32 + kq * 8);
        Bw1[ks] = *(const half8*)(Wc + (size_t)(2048 + nrow) * 1024 + ks * 32 + kq * 8);
    }

    // ---- epilogue lane mapping (round-2/5/6 verified) ----
    const int eunit = ubase + (lane & 3);
    const int erow0 = rowbase + (lane >> 2);   // m-subtile 0; +16 for subtile 1
    float4 bz0 = make_float4(bias[eunit], bias[512 + eunit],
                             bias[1024 + eunit], bias[1536 + eunit]);
    float4 bz1 = make_float4(bias[2048 + eunit], bias[2048 + 512 + eunit],
                             bias[2048 + 1024 + eunit], bias[2048 + 1536 + eunit]);

    float creg[2][2], hreg[2][2];
#pragma unroll
    for (int mt = 0; mt < 2; ++mt) {
        creg[0][mt] = c0in[(erow0 + mt * 16) * 512 + eunit];
        creg[1][mt] = c0in[131072 + (erow0 + mt * 16) * 512 + eunit];
        hreg[0][mt] = 0.f; hreg[1][mt] = 0.f;
    }

// per-thread gate: wait until my oct's 8 producers of phase PPH signalled.
// The atomic load's compiler waitcnt (vmcnt(0)) drains ALL in-flight asm
// loads into their tmps -> later counted waits become no-ops (safe).
#define GATE(PPH, OCT) do {                                                   \
    unsigned* fp = flags + ((size_t)((PPH) * 4 + m) * 8 + (OCT)) * 32;        \
    while (__hip_atomic_load(fp, __ATOMIC_RELAXED,                            \
                             __HIP_MEMORY_SCOPE_SYSTEM) != 8u)                \
        __builtin_amdgcn_s_sleep(1);                                          \
} while (0)

// plain CACHED 16B loads of k-half `cs` (0/1) of the 64-row tile at BASE
// (row stride 1024B) into tmp[TB..TB+7]. Issue order defines vmcnt drains.
#define ISSUE_CHUNK(BASE, cs, TB) do {                                        \
    _Pragma("unroll")                                                         \
    for (int j = 0; j < 8; ++j) {                                             \
        int g = j * 256 + tid;                                                \
        int voff = (g >> 5) * 1024 + (cs) * 512 + (g & 31) * 16;              \
        asm volatile("global_load_dwordx4 %0, %1, %2"                         \
            : "=v"(tmp[(TB) + j]) : "v"(voff), "s"(BASE) : "memory");         \
    } } while (0)

// drain 8 loads (oldest-first) into LDS buffer `par` with XOR swizzle.
// NB = (outstanding when entering) - 1; post-gate instances are no-ops.
#define WRITE_CHUNK(par, TB, NB) do {                                         \
    _Pragma("unroll")                                                         \
    for (int j = 0; j < 8; ++j) {                                             \
        asm volatile("s_waitcnt vmcnt(%0)" :: "i"((NB) - j) : "memory");      \
        int g = j * 256 + tid;                                                \
        int row = g >> 5, bc = g & 31;                                        \
        *(i32x4*)(ldsraw + (par) * 32768 + row * 512 +                        \
                  ((bc ^ (row & 7)) * 16)) = tmp[(TB) + j];                   \
    } } while (0)

// 8 k-steps of MFMA from LDS buffer `par` against B fragments BW[CO..CO+7]
#define MFMA_CHUNK(par, CO, BW) do {                                          \
    _Pragma("unroll")                                                         \
    for (int ks = 0; ks < 8; ++ks) {                                          \
        half8 a0 = *(const half8*)(ldsraw + (par) * 32768 + lrow * 512 +      \
                      (((kq + 4 * ks) ^ sw) * 16));                           \
        half8 a1 = *(const half8*)(ldsraw + (par) * 32768 +                   \
                      (lrow + 16) * 512 + (((kq + 4 * ks) ^ sw) * 16));       \
        acc0 = __builtin_amdgcn_mfma_f32_16x16x32_f16(a0, (BW)[(CO) + ks],    \
                                                      acc0, 0, 0, 0);         \
        acc1 = __builtin_amdgcn_mfma_f32_16x16x32_f16(a1, (BW)[(CO) + ks],    \
                                                      acc1, 0, 0, 0);         \
    } } while (0)

// chunk order: h0 (k512-767, BW[16..23]), h1 (k768-1023, BW[24..31]),
//              x0 (k0-255,   BW[0..7]),   x1 (k256-511,  BW[8..15])
// h-chunks issued UNGATED (producer flag polled one phase earlier => data
// complete; addresses write-once => caches never stale). h-staging and
// h0-MFMA overlap producer lag; per-thread GATEs sit only before x-issues.
#define PHASE(PH, WAIT, XSRC, HSRC, BW, BZ, CREG, HREG, HDST) do {            \
    const char* bx = (const char*)(XSRC) + (size_t)m0 * 1024;                 \
    const char* bh = (const char*)(HSRC) + (size_t)m0 * 1024;                 \
    i32x4 tmp[16];                                                            \
    ISSUE_CHUNK(bh, 0, 0);                                                    \
    ISSUE_CHUNK(bh, 1, 8);                                                    \
    __syncthreads();                                                          \
    f32x4 acc0 = {0.f,0.f,0.f,0.f}, acc1 = {0.f,0.f,0.f,0.f};                 \
    WRITE_CHUNK(0, 0, 15);          /* h0 -> par0 (active, r14-exact) */      \
    __syncthreads();                                                          \
    MFMA_CHUNK(0, 16, BW);          /* h0 MFMA: ungated, under lag */         \
    if (WAIT) GATE((PH) - 1, octlo);/* my x0 producer ready; drains h1 */     \
    ISSUE_CHUNK(bx, 0, 0);                                                    \
    WRITE_CHUNK(1, 8, 15);          /* h1 -> par1 (no-op post-gate) */        \
    __syncthreads();                                                          \
    if (WAIT) GATE((PH) - 1, octhi);/* my x1 producer ready; drains x0 */     \
    ISSUE_CHUNK(bx, 1, 8);                                                    \
    MFMA_CHUNK(1, 24, BW);          /* h1 MFMA overlaps x1 flight */          \
    WRITE_CHUNK(0, 0, 15);          /* x0 -> par0 (no-op post-gate) */        \
    __syncthreads();                                                          \
    MFMA_CHUNK(0, 0, BW);           /* x0 MFMA overlaps x1 flight */          \
    WRITE_CHUNK(1, 8, 7);           /* x1 -> par1 (active, exact) */          \
    __syncthreads();                                                          \
    MFMA_CHUNK(1, 8, BW);                                                     \
    /* ---- epilogue: transpose, cell, LDS-gather, coalesced 16B flush ---- */ \
    float* scrw = (float*)(ldsraw + w * 1024);                                \
    h16* hbuf = (h16*)(ldsraw + 8192);                                        \
    _Pragma("unroll")                                                         \
    for (int mt = 0; mt < 2; ++mt) {                                          \
        f32x4 accv = mt ? acc1 : acc0;                                        \
        _Pragma("unroll")                                                     \
        for (int rr = 0; rr < 4; ++rr)                                        \
            scrw[(kq * 4 + rr) * 16 + mcol] = accv[rr];                       \
        float4 g4 = *(const float4*)&scrw[(lane >> 2) * 16 + (lane & 3) * 4]; \
        float iv = sigf(g4.x + (BZ).x);                                       \
        float fv = sigf(g4.y + (BZ).y);                                       \
        float gv = tanhf_(g4.z + (BZ).z);                                     \
        float ov = sigf(g4.w + (BZ).w);                                       \
        float cc = fv * (CREG)[mt] + iv * gv;                                 \
        float hh = ov * tanhf_(cc);                                           \
        (CREG)[mt] = cc; (HREG)[mt] = hh;                                     \
        hbuf[(lrloc + mt * 16) * 8 + luloc] = (h16)hh;                        \
    }                                                                         \
    __syncthreads();                                                          \
    if (tid < 64) {                                                           \
        i32x4 hv16 = *(const i32x4*)(ldsraw + 8192 + tid * 16);               \
        int voff = (m0 + tid) * 1024 + u0 * 2;                                \
        asm volatile("global_store_dwordx4 %0, %1, %2 sc0 sc1"                \
            :: "v"(voff), "v"(hv16), "s"(HDST) : "memory");                   \
    }                                                                         \
    asm volatile("s_waitcnt vmcnt(0)" ::: "memory");                          \
    __syncthreads();                                                          \
    if (tid == 0)                                                             \
        __hip_atomic_fetch_add(flags + (((PH) * 4 + m) * 8 + myoct) * 32, 1u, \
                               __ATOMIC_RELAXED, __HIP_MEMORY_SCOPE_AGENT);   \
} while (0)

#pragma unroll 1
    for (int t = 0; t < TT; ++t) {
        const h16* x0src = t ? (H1 + (size_t)(t - 1) * 131072) : Xinit;
        const h16* h0src = t ? (H0 + (size_t)(t - 1) * 131072) : H0init;
        // layer 0 (phase 2t): A = [x0src | h0src] -> H0[t]
        PHASE(2 * t, t > 0, x0src, h0src, Bw0, bz0, creg[0], hreg[0],
              (H0 + (size_t)t * 131072));
        const h16* h1src = t ? (H1 + (size_t)(t - 1) * 131072) : H1init;
        // layer 1 (phase 2t+1): A = [H0[t] | h1src] -> H1[t]
        PHASE(2 * t + 1, 1, (H0 + (size_t)t * 131072), h1src, Bw1, bz1,
              creg[1], hreg[1], (H1 + (size_t)t * 131072));
    }

    // ---- final hT / cT (normal stores; kernel-end release flushes) ----
#pragma unroll
    for (int mt = 0; mt < 2; ++mt) {
        int idx = (erow0 + mt * 16) * 512 + eunit;
        h_st[idx]          = hreg[0][mt];
        h_st[131072 + idx] = hreg[1][mt];
        c_st[idx]          = creg[0][mt];
        c_st[131072 + idx] = creg[1][mt];
    }
}

// ---------------- final FC over all stored h1(t): (T*B) x 7, K=512 -----------
__global__ __launch_bounds__(256) void fc_kernel(
    const h16* __restrict__ H1, const float* __restrict__ Wfc,
    const float* __restrict__ bfc, float* __restrict__ out)
{
    __shared__ float wl[NO * 512];
    for (int i = threadIdx.x; i < NO * 512; i += 256) wl[i] = Wfc[i];
    __syncthreads();
    const int wave = threadIdx.x >> 6, lane = threadIdx.x & 63;
    const int row = blockIdx.x * 4 + wave;   // row = t*256 + b
    const h16* hr = H1 + (size_t)row * 512;
    float acc[NO] = {0, 0, 0, 0, 0, 0, 0};
#pragma unroll
    for (int i = 0; i < 8; ++i) {
        float hv = (float)hr[i * 64 + lane];
#pragma unroll
        for (int o = 0; o < NO; ++o) acc[o] += hv * wl[o * 512 + i * 64 + lane];
    }
#pragma unroll
    for (int o = 0; o < NO; ++o)
#pragma unroll
        for (int off = 32; off; off >>= 1) acc[o] += __shfl_down(acc[o], off);
    if (lane == 0) {
        const int t = row >> 8, b = row & 255;
#pragma unroll
        for (int o = 0; o < NO; ++o) out[b * (TT * NO) + t * NO + o] = acc[o] + bfc[o];
    }
}

extern "C" void kernel_launch(void* const* d_in, const int* in_sizes, int n_in,
                              void* d_out, int out_size, void* d_ws, size_t ws_size,
                              hipStream_t stream)
{
    (void)in_sizes; (void)n_in; (void)out_size; (void)ws_size;
    const float* x   = (const float*)d_in[0];
    const float* h0  = (const float*)d_in[1];
    const float* c0  = (const float*)d_in[2];
    const float* Wih = (const float*)d_in[3];
    const float* Whh = (const float*)d_in[4];
    const float* bih = (const float*)d_in[5];
    const float* bhh = (const float*)d_in[6];
    const float* Wfc = (const float*)d_in[7];
    const float* bfc = (const float*)d_in[8];

    float* outf = (float*)d_out;                 // decoded (256*64*7)
    float* h_st = outf + 114688;                 // hT (2,256,512)
    float* c_st = h_st + 262144;                 // cT (2,256,512)

    char* ws = (char*)d_ws;
    h16*      Wc     = (h16*)ws;                         // 8 MB
    float*    bias   = (float*)(ws + 8388608);           // 16 KB
    h16*      Xinit  = (h16*)(ws + 8404992);             // 256 KB
    h16*      H0init = (h16*)(ws + 8667136);             // 256 KB
    h16*      H1init = (h16*)(ws + 8929280);             // 256 KB
    h16*      H0     = (h16*)(ws + 9191424);             // 16 MB (64 steps)
    h16*      H1     = (h16*)(ws + 25968640);            // 16 MB (64 steps)
    unsigned* flags  = (unsigned*)(ws + 42745856);       // 512 KB

    prologue<<<3728, 256, 0, stream>>>(Wih, Whh, Wc, x, h0, bih, bhh,
                                       Xinit, H0init, H1init, bias, flags);
    lstm_persist<<<256, 256, 0, stream>>>(Wc, bias, c0, Xinit, H0init, H1init,
                                          H0, H1, h_st, c_st, flags);
    fc_kernel<<<4096, 256, 0, stream>>>(H1, Wfc, bfc, outf);
}

// Round 14
// 589.677 us; speedup vs baseline: 1.5960x; 1.0493x over previous
//
#include <hip/hip_runtime.h>

// LSTM decoder: B=256, H=512, L=2, T=64, O=7
// Round 20 = r18 (618.8us PASS, banked) + MERGED GATE only:
//  - r19's failure mechanism pinned: it held 64 VGPRs of asm-load tmps live
//    across the gate spin loop -> spill-before-load-return corruption.
//    RULE: at most ~8 tmp quads may cross a spin loop (r18's proven level).
//  - this round: r18 byte-identical EXCEPT the two per-thread gates merge
//    into one GATE2 at the first gate site (both octs, one spin). Both
//    gates waited on the SAME producer phase (flags arrive together), so
//    no added wait; saves one spin + one forced vmcnt(0) drain per phase,
//    issues x1 one barrier earlier, and lets x0's flight extend under
//    barrier #3 + MFMA h1.
//  - every counted wait is ACTIVE-EXACT r14 arithmetic on both WAIT paths
//    (no dependence on gate drains): WRITE h1 NB=15 handles 16-outstanding
//    ungated / no-ops gated; WRITE x0 NB=15 = r14-verbatim (x0+x1=16 out);
//    WRITE x1 NB=7 exact. Register liveness at GATE2 = tmp[8..15] (32
//    VGPRs) = r18's proven crossing. MFMA order h0,h1,x0,x1 -> bit-identical.
//  - epilogue r14-verbatim (store -> vmcnt(0) -> barrier -> flag on a quiet
//    bus; r17 proved this ordering matters). Revert point: r18.

#define TT 64
#define NO 7

typedef _Float16 h16;
typedef __attribute__((ext_vector_type(8))) _Float16 half8;
typedef __attribute__((ext_vector_type(4))) float f32x4;
typedef __attribute__((ext_vector_type(4))) int i32x4;

__device__ __forceinline__ float sigf(float x)   { return 1.f / (1.f + __expf(-x)); }
__device__ __forceinline__ float tanhf_(float x) { return 1.f - 2.f / (__expf(2.f * x) + 1.f); }

// ---------------- fused prologue (r14, proven) ------------------------------
// blocks [0,2048): pack [W_ih | W_hh] -> f16 Wc[l][n][k], k-major (8 h16/thr)
// blocks [2048,3600): Xinit/H0init/H1init + bias
// blocks [3600,3728): zero the 512KB flag array (16B/thr)
__global__ __launch_bounds__(256) void prologue(
    const float* __restrict__ Wih, const float* __restrict__ Whh,
    h16* __restrict__ Wc,
    const float* __restrict__ x, const float* __restrict__ h0,
    const float* __restrict__ bih, const float* __restrict__ bhh,
    h16* __restrict__ Xinit, h16* __restrict__ H0init, h16* __restrict__ H1init,
    float* __restrict__ bias, unsigned* __restrict__ flags)
{
    int blk = blockIdx.x;
    if (blk < 2048) {
        size_t gid = (size_t)blk * 256 + threadIdx.x;
        size_t base = gid * 8;
        int l = (int)(base >> 21);
        int rem = (int)(base & ((1u << 21) - 1));
        int n = rem >> 10;
        int k = rem & 1023;
        const float* src = (k < 512)
            ? (Wih + ((size_t)l * 2048 + n) * 512 + k)
            : (Whh + ((size_t)l * 2048 + n) * 512 + (k - 512));
        const float4* s4 = (const float4*)src;
        float4 a = s4[0];
        float4 b = s4[1];
        half8 o;
        o[0] = (h16)a.x; o[1] = (h16)a.y; o[2] = (h16)a.z; o[3] = (h16)a.w;
        o[4] = (h16)b.x; o[5] = (h16)b.y; o[6] = (h16)b.z; o[7] = (h16)b.w;
        *(half8*)(Wc + base) = o;
        return;
    }
    blk -= 2048;
    if (blk < 1552) {
        int i = blk * 256 + threadIdx.x;
        if (i < 131072) { Xinit[i]  = (h16)x[i];           return; }
        i -= 131072;
        if (i < 131072) { H0init[i] = (h16)h0[i];          return; }
        i -= 131072;
        if (i < 131072) { H1init[i] = (h16)h0[131072 + i]; return; }
        i -= 131072;
        if (i < 4096) bias[i] = bih[i] + bhh[i];
        return;
    }
    blk -= 1552;
    // flags zero: 128 blocks x 256 threads x 16B = 512KB
    i32x4 z = {0, 0, 0, 0};
    *(i32x4*)(flags + (size_t)(blk * 256 + threadIdx.x) * 4) = z;
}

// ---------------- persistent LSTM ------------------------------------------
// 256 WGs x 256 thr, 1 WG/CU. XCD-pinned: m = (wg&7)>>1, us = (wg>>3)+(wg&1)*32.
// WG: 64-row m-tile x 8 h-units. Wave w: rows (w>>1)*32..+32, units (w&1)*4..+4
// (16 gate-cols, col = 4*ulocal + gate).
__global__ __launch_bounds__(256, 1) void lstm_persist(
    const h16* __restrict__ Wc, const float* __restrict__ bias,
    const float* __restrict__ c0in,
    const h16* __restrict__ Xinit, const h16* __restrict__ H0init,
    const h16* __restrict__ H1init,
    h16* __restrict__ H0, h16* __restrict__ H1,
    float* __restrict__ h_st, float* __restrict__ c_st,
    unsigned* __restrict__ flags)
{
    __shared__ char ldsraw[65536];   // 2 x 32KB A-chunk double buffer

    const int wg   = blockIdx.x;
    const int m    = (wg & 7) >> 1;               // XCD-pinned m-group
    const int us   = (wg >> 3) + (wg & 1) * 32;   // unit slice 0..63
    const int myoct = us >> 3;
    const int tid  = threadIdx.x, w = tid >> 6, lane = tid & 63;
    const int u0   = us * 8;
    const int m0   = m * 64;
    const int rowbase = m0 + (w >> 1) * 32;
    const int ubase   = u0 + (w & 1) * 4;
    const int mcol = lane & 15, kq = lane >> 4;
    const int nrow = (mcol & 3) * 512 + ubase + (mcol >> 2);
    const int lrow = (w >> 1) * 32 + mcol;     // local row of m-subtile 0
    const int sw   = mcol & 7;                 // LDS XOR swizzle key
    const int lrloc = (w >> 1) * 32 + (lane >> 2);   // epilogue local row
    const int luloc = (w & 1) * 4 + (lane & 3);      // epilogue local unit
    const int octlo = (tid & 31) >> 3;         // producer oct of my x0 loads
    const int octhi = 4 + ((tid & 31) >> 3);   // producer oct of my x1 loads

    // ---- B fragments for both layers -> registers/AGPRs (loaded once) ----
    half8 Bw0[32], Bw1[32];
#pragma unroll
    for (int ks = 0; ks < 32; ++ks) {
        Bw0[ks] = *(const half8*)(Wc + (size_t)nrow * 1024 + ks * 32 + kq * 8);
        Bw1[ks] = *(const half8*)(Wc + (size_t)(2048 + nrow) * 1024 + ks * 32 + kq * 8);
    }

    // ---- epilogue lane mapping (round-2/5/6 verified) ----
    const int eunit = ubase + (lane & 3);
    const int erow0 = rowbase + (lane >> 2);   // m-subtile 0; +16 for subtile 1
    float4 bz0 = make_float4(bias[eunit], bias[512 + eunit],
                             bias[1024 + eunit], bias[1536 + eunit]);
    float4 bz1 = make_float4(bias[2048 + eunit], bias[2048 + 512 + eunit],
                             bias[2048 + 1024 + eunit], bias[2048 + 1536 + eunit]);

    float creg[2][2], hreg[2][2];
#pragma unroll
    for (int mt = 0; mt < 2; ++mt) {
        creg[0][mt] = c0in[(erow0 + mt * 16) * 512 + eunit];
        creg[1][mt] = c0in[131072 + (erow0 + mt * 16) * 512 + eunit];
        hreg[0][mt] = 0.f; hreg[1][mt] = 0.f;
    }

// merged per-thread gate: spin until BOTH of my octs of phase PPH reach 8.
// Both flags belong to the SAME producer phase (arrive together), so this
// costs no extra wait vs gating octlo alone. The atomic loads' compiler
// waitcnt (vmcnt(0)) additionally drains all in-flight asm loads.
#define GATE2(PPH) do {                                                       \
    const unsigned* fp0 =                                                     \
        flags + ((size_t)((PPH) * 4 + m) * 8 + octlo) * 32;                   \
    const unsigned* fp1 =                                                     \
        flags + ((size_t)((PPH) * 4 + m) * 8 + octhi) * 32;                   \
    for (;;) {                                                                \
        unsigned a = __hip_atomic_load(fp0, __ATOMIC_RELAXED,                 \
                                       __HIP_MEMORY_SCOPE_SYSTEM);            \
        unsigned b = __hip_atomic_load(fp1, __ATOMIC_RELAXED,                 \
                                       __HIP_MEMORY_SCOPE_SYSTEM);            \
        if (a == 8u && b == 8u) break;                                        \
        __builtin_amdgcn_s_sleep(1);                                          \
    }                                                                         \
} while (0)

// plain CACHED 16B loads of k-half `cs` (0/1) of the 64-row tile at BASE
// (row stride 1024B) into tmp[TB..TB+7]. Issue order defines vmcnt drains.
#define ISSUE_CHUNK(BASE, cs, TB) do {                                        \
    _Pragma("unroll")                                                         \
    for (int j = 0; j < 8; ++j) {                                             \
        int g = j * 256 + tid;                                                \
        int voff = (g >> 5) * 1024 + (cs) * 512 + (g & 31) * 16;              \
        asm volatile("global_load_dwordx4 %0, %1, %2"                         \
            : "=v"(tmp[(TB) + j]) : "v"(voff), "s"(BASE) : "memory");         \
    } } while (0)

// drain 8 loads (oldest-first) into LDS buffer `par` with XOR swizzle.
// NB = (outstanding when entering, ungated path) - 1; active counts are
// r14-exact, gate drains only turn them into no-ops (never under-wait).
#define WRITE_CHUNK(par, TB, NB) do {                                         \
    _Pragma("unroll")                                                         \
    for (int j = 0; j < 8; ++j) {                                             \
        asm volatile("s_waitcnt vmcnt(%0)" :: "i"((NB) - j) : "memory");      \
        int g = j * 256 + tid;                                                \
        int row = g >> 5, bc = g & 31;                                        \
        *(i32x4*)(ldsraw + (par) * 32768 + row * 512 +                        \
                  ((bc ^ (row & 7)) * 16)) = tmp[(TB) + j];                   \
    } } while (0)

// 8 k-steps of MFMA from LDS buffer `par` against B fragments BW[CO..CO+7]
#define MFMA_CHUNK(par, CO, BW) do {                                          \
    _Pragma("unroll")                                                         \
    for (int ks = 0; ks < 8; ++ks) {                                          \
        half8 a0 = *(const half8*)(ldsraw + (par) * 32768 + lrow * 512 +      \
                      (((kq + 4 * ks) ^ sw) * 16));                           \
        half8 a1 = *(const half8*)(ldsraw + (par) * 32768 +                   \
                      (lrow + 16) * 512 + (((kq + 4 * ks) ^ sw) * 16));       \
        acc0 = __builtin_amdgcn_mfma_f32_16x16x32_f16(a0, (BW)[(CO) + ks],    \
                                                      acc0, 0, 0, 0);         \
        acc1 = __builtin_amdgcn_mfma_f32_16x16x32_f16(a1, (BW)[(CO) + ks],    \
                                                      acc1, 0, 0, 0);         \
    } } while (0)

// chunk order: h0 (k512-767, BW[16..23]), h1 (k768-1023, BW[24..31]),
//              x0 (k0-255,   BW[0..7]),   x1 (k256-511,  BW[8..15])
// h-chunks issued UNGATED (producer confirmed one phase earlier, wave-level;
// write-once addresses => caches never stale). MERGED GATE2 sits after the
// h0-MFMA (which overlaps producer lag); x loads issue post-gate only.
#define PHASE(PH, WAIT, XSRC, HSRC, BW, BZ, CREG, HREG, HDST) do {            \
    const char* bx = (const char*)(XSRC) + (size_t)m0 * 1024;                 \
    const char* bh = (const char*)(HSRC) + (size_t)m0 * 1024;                 \
    i32x4 tmp[16];                                                            \
    ISSUE_CHUNK(bh, 0, 0);                                                    \
    ISSUE_CHUNK(bh, 1, 8);                                                    \
    __syncthreads();                                                          \
    f32x4 acc0 = {0.f,0.f,0.f,0.f}, acc1 = {0.f,0.f,0.f,0.f};                 \
    WRITE_CHUNK(0, 0, 15);          /* h0 -> par0 (active, r14-exact) */      \
    __syncthreads();                                                          \
    MFMA_CHUNK(0, 16, BW);          /* h0 MFMA: ungated, under lag */         \
    if (WAIT) GATE2((PH) - 1);      /* both x producers; one spin; only */    \
    ISSUE_CHUNK(bx, 0, 0);          /*   tmp[8..15] live across (32 VGPR) */  \
    WRITE_CHUNK(1, 8, 15);          /* h1: 16-out exact / no-op gated */      \
    __syncthreads();                                                          \
    ISSUE_CHUNK(bx, 1, 8);                                                    \
    MFMA_CHUNK(1, 24, BW);          /* h1 MFMA; x0+x1 in flight under it */   \
    WRITE_CHUNK(0, 0, 15);          /* x0: 16-out, r14-exact counts */        \
    __syncthreads();                                                          \
    MFMA_CHUNK(0, 0, BW);           /* x0 MFMA overlaps x1 tail */            \
    WRITE_CHUNK(1, 8, 7);           /* x1: 8-out exact */                     \
    __syncthreads();                                                          \
    MFMA_CHUNK(1, 8, BW);                                                     \
    /* ---- epilogue: transpose, cell, LDS-gather, coalesced 16B flush ---- */ \
    float* scrw = (float*)(ldsraw + w * 1024);                                \
    h16* hbuf = (h16*)(ldsraw + 8192);                                        \
    _Pragma("unroll")                                                         \
    for (int mt = 0; mt < 2; ++mt) {                                          \
        f32x4 accv = mt ? acc1 : acc0;                                        \
        _Pragma("unroll")                                                     \
        for (int rr = 0; rr < 4; ++rr)                                        \
            scrw[(kq * 4 + rr) * 16 + mcol] = accv[rr];                       \
        float4 g4 = *(const float4*)&scrw[(lane >> 2) * 16 + (lane & 3) * 4]; \
        float iv = sigf(g4.x + (BZ).x);                                       \
        float fv = sigf(g4.y + (BZ).y);                                       \
        float gv = tanhf_(g4.z + (BZ).z);                                     \
        float ov = sigf(g4.w + (BZ).w);                                       \
        float cc = fv * (CREG)[mt] + iv * gv;                                 \
        float hh = ov * tanhf_(cc);                                           \
        (CREG)[mt] = cc; (HREG)[mt] = hh;                                     \
        hbuf[(lrloc + mt * 16) * 8 + luloc] = (h16)hh;                        \
    }                                                                         \
    __syncthreads();                                                          \
    if (tid < 64) {                                                           \
        i32x4 hv16 = *(const i32x4*)(ldsraw + 8192 + tid * 16);               \
        int voff = (m0 + tid) * 1024 + u0 * 2;                                \
        asm volatile("global_store_dwordx4 %0, %1, %2 sc0 sc1"                \
            :: "v"(voff), "v"(hv16), "s"(HDST) : "memory");                   \
    }                                                                         \
    asm volatile("s_waitcnt vmcnt(0)" ::: "memory");                          \
    __syncthreads();                /* flag goes out on a quiet bus (r17) */  \
    if (tid == 0)                                                             \
        __hip_atomic_fetch_add(flags + (((PH) * 4 + m) * 8 + myoct) * 32, 1u, \
                               __ATOMIC_RELAXED, __HIP_MEMORY_SCOPE_AGENT);   \
} while (0)

#pragma unroll 1
    for (int t = 0; t < TT; ++t) {
        const h16* x0src = t ? (H1 + (size_t)(t - 1) * 131072) : Xinit;
        const h16* h0src = t ? (H0 + (size_t)(t - 1) * 131072) : H0init;
        // layer 0 (phase 2t): A = [x0src | h0src] -> H0[t]
        PHASE(2 * t, t > 0, x0src, h0src, Bw0, bz0, creg[0], hreg[0],
              (H0 + (size_t)t * 131072));
        const h16* h1src = t ? (H1 + (size_t)(t - 1) * 131072) : H1init;
        // layer 1 (phase 2t+1): A = [H0[t] | h1src] -> H1[t]
        PHASE(2 * t + 1, 1, (H0 + (size_t)t * 131072), h1src, Bw1, bz1,
              creg[1], hreg[1], (H1 + (size_t)t * 131072));
    }

    // ---- final hT / cT (normal stores; kernel-end release flushes) ----
#pragma unroll
    for (int mt = 0; mt < 2; ++mt) {
        int idx = (erow0 + mt * 16) * 512 + eunit;
        h_st[idx]          = hreg[0][mt];
        h_st[131072 + idx] = hreg[1][mt];
        c_st[idx]          = creg[0][mt];
        c_st[131072 + idx] = creg[1][mt];
    }
}

// ---------------- final FC over all stored h1(t): (T*B) x 7, K=512 -----------
__global__ __launch_bounds__(256) void fc_kernel(
    const h16* __restrict__ H1, const float* __restrict__ Wfc,
    const float* __restrict__ bfc, float* __restrict__ out)
{
    __shared__ float wl[NO * 512];
    for (int i = threadIdx.x; i < NO * 512; i += 256) wl[i] = Wfc[i];
    __syncthreads();
    const int wave = threadIdx.x >> 6, lane = threadIdx.x & 63;
    const int row = blockIdx.x * 4 + wave;   // row = t*256 + b
    const h16* hr = H1 + (size_t)row * 512;
    float acc[NO] = {0, 0, 0, 0, 0, 0, 0};
#pragma unroll
    for (int i = 0; i < 8; ++i) {
        float hv = (float)hr[i * 64 + lane];
#pragma unroll
        for (int o = 0; o < NO; ++o) acc[o] += hv * wl[o * 512 + i * 64 + lane];
    }
#pragma unroll
    for (int o = 0; o < NO; ++o)
#pragma unroll
        for (int off = 32; off; off >>= 1) acc[o] += __shfl_down(acc[o], off);
    if (lane == 0) {
        const int t = row >> 8, b = row & 255;
#pragma unroll
        for (int o = 0; o < NO; ++o) out[b * (TT * NO) + t * NO + o] = acc[o] + bfc[o];
    }
}

extern "C" void kernel_launch(void* const* d_in, const int* in_sizes, int n_in,
                              void* d_out, int out_size, void* d_ws, size_t ws_size,
                              hipStream_t stream)
{
    (void)in_sizes; (void)n_in; (void)out_size; (void)ws_size;
    const float* x   = (const float*)d_in[0];
    const float* h0  = (const float*)d_in[1];
    const float* c0  = (const float*)d_in[2];
    const float* Wih = (const float*)d_in[3];
    const float* Whh = (const float*)d_in[4];
    const float* bih = (const float*)d_in[5];
    const float* bhh = (const float*)d_in[6];
    const float* Wfc = (const float*)d_in[7];
    const float* bfc = (const float*)d_in[8];

    float* outf = (float*)d_out;                 // decoded (256*64*7)
    float* h_st = outf + 114688;                 // hT (2,256,512)
    float* c_st = h_st + 262144;                 // cT (2,256,512)

    char* ws = (char*)d_ws;
    h16*      Wc     = (h16*)ws;                         // 8 MB
    float*    bias   = (float*)(ws + 8388608);           // 16 KB
    h16*      Xinit  = (h16*)(ws + 8404992);             // 256 KB
    h16*      H0init = (h16*)(ws + 8667136);             // 256 KB
    h16*      H1init = (h16*)(ws + 8929280);             // 256 KB
    h16*      H0     = (h16*)(ws + 9191424);             // 16 MB (64 steps)
    h16*      H1     = (h16*)(ws + 25968640);            // 16 MB (64 steps)
    unsigned* flags  = (unsigned*)(ws + 42745856);       // 512 KB

    prologue<<<3728, 256, 0, stream>>>(Wih, Whh, Wc, x, h0, bih, bhh,
                                       Xinit, H0init, H1init, bias, flags);
    lstm_persist<<<256, 256, 0, stream>>>(Wc, bias, c0, Xinit, H0init, H1init,
                                          H0, H1, h_st, c_st, flags);
    fc_kernel<<<4096, 256, 0, stream>>>(H1, Wfc, bfc, outf);
}